// Round 12
// baseline (102.025 us; speedup 1.0000x reference)
//
#include <hip/hip_runtime.h>

typedef __attribute__((ext_vector_type(4))) float f32x4;
typedef __attribute__((ext_vector_type(4))) int   i32x4;
typedef __attribute__((ext_vector_type(8))) int   i32x8;

#define DIM 256
#define D4  64    // float4 per row

// async global->LDS, 16B per lane; LDS dest = wave-uniform base + lane*16.
#define GLD_LDS16(g, l) __builtin_amdgcn_global_load_lds(                      \
    (const __attribute__((address_space(1))) void*)(g),                        \
    (__attribute__((address_space(3))) void*)(l), 16, 0, 0)

// wait for all but the newest N VMEM ops, then barrier (counted prefetch).
#define TILE_WAIT(N) asm volatile("s_waitcnt vmcnt(" #N ")\n\ts_barrier" ::: "memory")

// One wave per row. Rows [0,N): exact fp32 pos_sim -> posPart[row] + normalized
// pk -> fp8 e4m3. Rows [N,N+M): normalized nv -> fp8. Block 0 zeroes `out`.
__global__ __launch_bounds__(256) void normalize_kernel(
    const float4* __restrict__ pk, const float4* __restrict__ pv,
    const float4* __restrict__ nv, unsigned int* __restrict__ pkn,
    unsigned int* __restrict__ nvn, float* __restrict__ posPart,
    float* __restrict__ out, int N) {
  if (blockIdx.x == 0 && threadIdx.x == 0) out[0] = 0.f;
  int row  = blockIdx.x * 4 + (threadIdx.x >> 6);
  int lane = threadIdx.x & 63;
  if (row < N) {
    float4 x = pk[row * D4 + lane];
    float4 y = pv[row * D4 + lane];
    float skk = x.x*x.x + x.y*x.y + x.z*x.z + x.w*x.w;
    float svv = y.x*y.x + y.y*y.y + y.z*y.z + y.w*y.w;
    float skv = x.x*y.x + x.y*y.y + x.z*y.z + x.w*y.w;
#pragma unroll
    for (int m = 32; m >= 1; m >>= 1) {
      skk += __shfl_xor(skk, m, 64);
      svv += __shfl_xor(svv, m, 64);
      skv += __shfl_xor(skv, m, 64);
    }
    float nk  = fmaxf(sqrtf(skk), 1e-8f);
    float nvv = fmaxf(sqrtf(svv), 1e-8f);
    if (lane == 0) posPart[row] = skv / (nk * nvv);
    float rk = 1.0f / nk;
    int w = __builtin_amdgcn_cvt_pk_fp8_f32(x.x * rk, x.y * rk, 0, false);
    w = __builtin_amdgcn_cvt_pk_fp8_f32(x.z * rk, x.w * rk, w, true);
    pkn[(size_t)row * 64 + lane] = (unsigned int)w;
  } else {
    int r2 = row - N;
    float4 x = nv[r2 * D4 + lane];
    float s = x.x*x.x + x.y*x.y + x.z*x.z + x.w*x.w;
#pragma unroll
    for (int m = 32; m >= 1; m >>= 1) s += __shfl_xor(s, m, 64);
    float rn = 1.0f / fmaxf(sqrtf(s), 1e-8f);
    int w = __builtin_amdgcn_cvt_pk_fp8_f32(x.x * rn, x.y * rn, 0, false);
    w = __builtin_amdgcn_cvt_pk_fp8_f32(x.z * rn, x.w * rn, w, true);
    nvn[(size_t)r2 * 64 + lane] = (unsigned int)w;
  }
}

// Fused fp8 GEMM (MX 16x16x128, unit scales = exact fp8) + exp(sim/2) + row-sum.
// R18 = R9 (best, 98.9) + PHASE-SPLIT compute (the §5.5 regime-gate lever).
// Evidence: our structure was the "2-phase" row of the m228d/m230/m248 gate
// table -- stage + counted vmcnt + one barrier per tile, monolithic compute
// burst -- where T2/T5/occupancy grafts are all NULL (matches 6 in-session
// nulls). The table's positive lever is the fine per-phase interleave
// (m196: +28-41%; m218b setprio +21-25% once phases exist). Port: per tile,
// 2 kb-phases {ds_read 8 b128 -> s_barrier -> setprio(1) -> 16-MFMA cluster
// -> setprio(0) -> s_barrier}, B(t+3) stage split into two 2-load halves
// issued between phases. Phase barriers are schedule-shaping only (buffer t
// is stable all tile; correctness barrier = TILE_WAIT, counts unchanged:
// per-tile VMEM totals identical, just reordered within the tile). Uniform
// control flow -> race-free. Per-element accumulation still kb0->kb1;
// epilogue sum order unchanged -> absmax 0. Macro-structure (persistent
// 256-row panel, 8 cgs, A-in-regs, 4-deep LDS B) identical to R9.
__global__ __launch_bounds__(512, 2) void gemm_lse_kernel(
    const unsigned char* __restrict__ gA, const unsigned char* __restrict__ gB,
    float* __restrict__ partial, int N) {
  __shared__ unsigned char Bs[4][32768];  // per buf: [2 kb][128 rows][8 chunks]

  const int tid  = threadIdx.x;
  const int lane = tid & 63;
  const int wv   = tid >> 6;      // 0..7
  const int wm   = wv >> 1;       // 0..3 : 64-row strip of the 256-row panel
  const int wn   = wv & 1;        // 0..1 : 64-col half of the 128-col tile
  const int l15  = lane & 15, q = lane >> 4;
  const int cg    = blockIdx.x;   // 0..7  : 1024-col group (fixed per XCD)
  const int panel = blockIdx.y;   // 0..31 : 256-row panel
  const int row0  = panel * 256;
  const int colBase = cg * 1024;
  const float kLog2eHalf = 0.72134752044448170f;  // log2(e)/2
  const int kUnitScale = 0x7F7F7F7F;              // e8m0 127 = 2^0 per byte

  // stage one kb-half of B(t) (2 GLD per thread).
  auto stageHalf = [&](int t, int kb) {
    const unsigned char* src = gB + (size_t)(colBase + t * 128) * 256;
    unsigned char* dst = &Bs[t & 3][0];
#pragma unroll
    for (int i = 0; i < 2; i++) {
      int c  = i * 512 + tid;            // chunk within this kb-half
      int r  = c >> 3;                   // 0..127
      int sc = ((c & 7) ^ (r & 7)) << 4; // pre-swizzled global source col
      GLD_LDS16(src + (size_t)r * 256 + kb * 128 + sc,
                dst + kb * 16384 + c * 16);
    }
  };

  // A fragments straight to registers, once (16 dwordx4 per thread).
  const unsigned char* aB = gA + (size_t)(row0 + wm * 64 + l15) * 256 + q * 32;
  i32x8 af[2][4];
#pragma unroll
  for (int kb = 0; kb < 2; kb++)
#pragma unroll
    for (int mi = 0; mi < 4; mi++)
      af[kb][mi] = *(const i32x8*)(aB + mi * 16 * 256 + kb * 128);
  __builtin_amdgcn_sched_barrier(0);   // pin: A loads issue before B stages

  stageHalf(0, 0); stageHalf(0, 1);
  stageHalf(1, 0); stageHalf(1, 1);
  stageHalf(2, 0); stageHalf(2, 1);
  __builtin_amdgcn_sched_barrier(0);

#pragma unroll
  for (int t = 0; t < 8; t++) {
    // Counted waits identical to R9 (per-tile VMEM totals unchanged).
    if      (t == 0) TILE_WAIT(7);
    else if (t == 1) TILE_WAIT(8);
    else if (t == 2) TILE_WAIT(9);
    else if (t == 3) TILE_WAIT(10);
    else if (t == 4) TILE_WAIT(10);
    else if (t == 5) TILE_WAIT(10);
    else if (t == 6) TILE_WAIT(6);
    else             TILE_WAIT(2);

    if (t < 5) { stageHalf(t + 3, 0); __builtin_amdgcn_sched_barrier(0); }

    const unsigned char* bufB = &Bs[t & 3][0];
    f32x4 acc[4][4];
#pragma unroll
    for (int mi = 0; mi < 4; mi++)
#pragma unroll
      for (int ni = 0; ni < 4; ni++) acc[mi][ni] = (f32x4){0.f, 0.f, 0.f, 0.f};

    // ---- phase 0 (kb=0): ds_read -> barrier -> MFMA cluster -> barrier ----
    i32x8 bf0[4];
#pragma unroll
    for (int ni = 0; ni < 4; ni++) {
      int r  = wn * 64 + ni * 16 + l15;           // 0..127
      int c0 = (q * 2)     ^ (r & 7);
      int c1 = (q * 2 + 1) ^ (r & 7);
      i32x4 lo = *(const i32x4*)(bufB + r * 128 + c0 * 16);
      i32x4 hi = *(const i32x4*)(bufB + r * 128 + c1 * 16);
      bf0[ni] = (i32x8){lo.x, lo.y, lo.z, lo.w, hi.x, hi.y, hi.z, hi.w};
    }
    __builtin_amdgcn_s_barrier();
    __builtin_amdgcn_s_setprio(1);
#pragma unroll
    for (int mi = 0; mi < 4; mi++)
#pragma unroll
      for (int ni = 0; ni < 4; ni++)
        acc[mi][ni] = __builtin_amdgcn_mfma_scale_f32_16x16x128_f8f6f4(
            bf0[ni], af[0][mi], acc[mi][ni],      // SWAPPED: D[col][row]
            0, 0, 0, kUnitScale, 0, kUnitScale);
    __builtin_amdgcn_s_setprio(0);
    __builtin_amdgcn_s_barrier();

    if (t < 5) { stageHalf(t + 3, 1); __builtin_amdgcn_sched_barrier(0); }

    // ---- phase 1 (kb=1) ----
    i32x8 bf1[4];
#pragma unroll
    for (int ni = 0; ni < 4; ni++) {
      int r  = wn * 64 + ni * 16 + l15;
      int c0 = (q * 2)     ^ (r & 7);
      int c1 = (q * 2 + 1) ^ (r & 7);
      i32x4 lo = *(const i32x4*)(bufB + 16384 + r * 128 + c0 * 16);
      i32x4 hi = *(const i32x4*)(bufB + 16384 + r * 128 + c1 * 16);
      bf1[ni] = (i32x8){lo.x, lo.y, lo.z, lo.w, hi.x, hi.y, hi.z, hi.w};
    }
    __builtin_amdgcn_s_barrier();
    __builtin_amdgcn_s_setprio(1);
#pragma unroll
    for (int mi = 0; mi < 4; mi++)
#pragma unroll
      for (int ni = 0; ni < 4; ni++)
        acc[mi][ni] = __builtin_amdgcn_mfma_scale_f32_16x16x128_f8f6f4(
            bf1[ni], af[1][mi], acc[mi][ni],
            0, 0, 0, kUnitScale, 0, kUnitScale);
    __builtin_amdgcn_s_setprio(0);
    __builtin_amdgcn_s_barrier();

    // epilogue (R4/R5-verified order): per mi, in-register sum + 2 shuffles.
    float s0, s1, s2, s3;
#pragma unroll
    for (int mi = 0; mi < 4; mi++) {
      float v = 0.f;
#pragma unroll
      for (int ni = 0; ni < 4; ni++)
#pragma unroll
        for (int rr = 0; rr < 4; rr++)
          v += __builtin_amdgcn_exp2f(acc[mi][ni][rr] * kLog2eHalf);
      v += __shfl_xor(v, 16, 64);
      v += __shfl_xor(v, 32, 64);
      if (mi == 0) s0 = v; else if (mi == 1) s1 = v;
      else if (mi == 2) s2 = v; else s3 = v;
    }
    float o = q == 0 ? s0 : q == 1 ? s1 : q == 2 ? s2 : s3;
    int slab = cg * 16 + t * 2 + wn;                // 64-col slab, 0..127
    partial[(size_t)slab * N + row0 + wm * 64 + q * 16 + l15] = o;
    __builtin_amdgcn_sched_barrier(0);   // pin: store issues before next stage
  }
}

// out = mean(ln(sum_j partial[j][row])) - 0.5*mean(posPart). UNCHANGED
// (partial is [M/64=128][N]).
__global__ __launch_bounds__(256) void finalize_kernel(
    const float* __restrict__ partial, const float* __restrict__ posPart,
    float* __restrict__ out, int N, int slabsPerGroup, float invN) {
  __shared__ float red[4][64];
  int t  = threadIdx.x;
  int rl = t & 63, g = t >> 6;
  int row = blockIdx.x * 64 + rl;
  const float* p = partial + (size_t)(g * slabsPerGroup) * N + row;
  float s = 0.f;
#pragma unroll 8
  for (int j = 0; j < slabsPerGroup; j++) s += p[(size_t)j * N];
  red[g][rl] = s;
  __syncthreads();
  if (t < 64) {
    float tot = red[0][rl] + red[1][rl] + red[2][rl] + red[3][rl];
    float v = __builtin_amdgcn_logf(tot) * 0.69314718055994531f
              - 0.5f * posPart[row];
#pragma unroll
    for (int m = 32; m >= 1; m >>= 1) v += __shfl_xor(v, m, 64);
    if (rl == 0) atomicAdd(out, v * invN);
  }
}

extern "C" void kernel_launch(void* const* d_in, const int* in_sizes, int n_in,
                              void* d_out, int out_size, void* d_ws, size_t ws_size,
                              hipStream_t stream) {
  const float* pk = (const float*)d_in[0];
  const float* pv = (const float*)d_in[1];
  const float* nv = (const float*)d_in[2];
  int N = in_sizes[0] / DIM;   // 8192
  int M = in_sizes[2] / DIM;   // 8192
  float* out = (float*)d_out;

  unsigned char* pkn = (unsigned char*)d_ws;                   // [N,256] fp8
  unsigned char* nvn = pkn + (size_t)N * DIM;                  // [M,256] fp8
  float* partial = (float*)(nvn + (size_t)M * DIM);            // [M/64][N] fp32
  float* posPart = partial + (size_t)(M / 64) * N;             // [N] fp32

  normalize_kernel<<<(N + M) / 4, 256, 0, stream>>>(
      (const float4*)pk, (const float4*)pv, (const float4*)nv,
      (unsigned int*)pkn, (unsigned int*)nvn, posPart, out, N);

  // grid: x = col-group (M/1024 = 8, one per XCD slot), y = row panel (32).
  gemm_lse_kernel<<<dim3(M / 1024, N / 256), 512, 0, stream>>>(
      pkn, nvn, partial, N);

  finalize_kernel<<<N / 64, 256, 0, stream>>>(
      partial, posPart, out, N, (M / 64) / 4, 1.0f / (float)N);
}

// Round 13
// 98.114 us; speedup vs baseline: 1.0399x; 1.0399x over previous
//
#include <hip/hip_runtime.h>

typedef __attribute__((ext_vector_type(4))) float f32x4;
typedef __attribute__((ext_vector_type(4))) int   i32x4;
typedef __attribute__((ext_vector_type(8))) int   i32x8;

#define DIM 256
#define D4  64    // float4 per row

// async global->LDS, 16B per lane; LDS dest = wave-uniform base + lane*16.
#define GLD_LDS16(g, l) __builtin_amdgcn_global_load_lds(                      \
    (const __attribute__((address_space(1))) void*)(g),                        \
    (__attribute__((address_space(3))) void*)(l), 16, 0, 0)

// wait for all but the newest N VMEM ops, then barrier (counted prefetch).
#define TILE_WAIT(N) asm volatile("s_waitcnt vmcnt(" #N ")\n\ts_barrier" ::: "memory")

// One wave per row. Rows [0,N): exact fp32 pos_sim -> posPart[row] + normalized
// pk -> fp8 e4m3. Rows [N,N+M): normalized nv -> fp8. Block 0 zeroes `out`
// (replaces the hipMemsetAsync dispatch; stream order -> visible to finalize).
__global__ __launch_bounds__(256) void normalize_kernel(
    const float4* __restrict__ pk, const float4* __restrict__ pv,
    const float4* __restrict__ nv, unsigned int* __restrict__ pkn,
    unsigned int* __restrict__ nvn, float* __restrict__ posPart,
    float* __restrict__ out, int N) {
  if (blockIdx.x == 0 && threadIdx.x == 0) out[0] = 0.f;
  int row  = blockIdx.x * 4 + (threadIdx.x >> 6);
  int lane = threadIdx.x & 63;
  if (row < N) {
    float4 x = pk[row * D4 + lane];
    float4 y = pv[row * D4 + lane];
    float skk = x.x*x.x + x.y*x.y + x.z*x.z + x.w*x.w;
    float svv = y.x*y.x + y.y*y.y + y.z*y.z + y.w*y.w;
    float skv = x.x*y.x + x.y*y.y + x.z*y.z + x.w*y.w;
#pragma unroll
    for (int m = 32; m >= 1; m >>= 1) {
      skk += __shfl_xor(skk, m, 64);
      svv += __shfl_xor(svv, m, 64);
      skv += __shfl_xor(skv, m, 64);
    }
    float nk  = fmaxf(sqrtf(skk), 1e-8f);
    float nvv = fmaxf(sqrtf(svv), 1e-8f);
    if (lane == 0) posPart[row] = skv / (nk * nvv);
    float rk = 1.0f / nk;
    int w = __builtin_amdgcn_cvt_pk_fp8_f32(x.x * rk, x.y * rk, 0, false);
    w = __builtin_amdgcn_cvt_pk_fp8_f32(x.z * rk, x.w * rk, w, true);
    pkn[(size_t)row * 64 + lane] = (unsigned int)w;
  } else {
    int r2 = row - N;
    float4 x = nv[r2 * D4 + lane];
    float s = x.x*x.x + x.y*x.y + x.z*x.z + x.w*x.w;
#pragma unroll
    for (int m = 32; m >= 1; m >>= 1) s += __shfl_xor(s, m, 64);
    float rn = 1.0f / fmaxf(sqrtf(s), 1e-8f);
    int w = __builtin_amdgcn_cvt_pk_fp8_f32(x.x * rn, x.y * rn, 0, false);
    w = __builtin_amdgcn_cvt_pk_fp8_f32(x.z * rn, x.w * rn, w, true);
    nvn[(size_t)r2 * 64 + lane] = (unsigned int)w;
  }
}

// Fused fp8 GEMM (MX 16x16x128, unit scales = exact fp8) + exp(sim/2) + row-sum.
// R19 = EXACT REVERT TO R9 (best measured, 98.9us). Session ledger: 12
// structural variants bracket the gemm at 33+-5us; only algorithmic epilogue
// wins reproduced (R4 axis-swap, R9 mi-outer interleave). All catalog grafts
// (T1/T2/T3/T4/T5, occupancy x2, phase-split) null or negative on this fused
// kernel -- consistent with the regime-gate table: isolated components of
// the deep-pipeline combo don't transfer without the full co-designed
// schedule. Macro: persistent 256-row panel, 8 cgs (XCD-local B), A-in-regs
// once, 4-deep LDS B, counted vmcnt; micro: mi-outer {8 MFMA -> epilogue
// slice} so exp2/add/shfl overlap the next mi's MFMAs. absmax 0.
__global__ __launch_bounds__(512, 2) void gemm_lse_kernel(
    const unsigned char* __restrict__ gA, const unsigned char* __restrict__ gB,
    float* __restrict__ partial, int N) {
  __shared__ unsigned char Bs[4][32768];  // per buf: [2 kb][128 rows][8 chunks]

  const int tid  = threadIdx.x;
  const int lane = tid & 63;
  const int wv   = tid >> 6;      // 0..7
  const int wm   = wv >> 1;       // 0..3 : 64-row strip of the 256-row panel
  const int wn   = wv & 1;        // 0..1 : 64-col half of the 128-col tile
  const int l15  = lane & 15, q = lane >> 4;
  const int cg    = blockIdx.x;   // 0..7  : 1024-col group (fixed per XCD)
  const int panel = blockIdx.y;   // 0..31 : 256-row panel
  const int row0  = panel * 256;
  const int colBase = cg * 1024;
  const float kLog2eHalf = 0.72134752044448170f;  // log2(e)/2
  const int kUnitScale = 0x7F7F7F7F;              // e8m0 127 = 2^0 per byte

  auto stageB = [&](int t) {
    const unsigned char* src = gB + (size_t)(colBase + t * 128) * 256;
    unsigned char* dst = &Bs[t & 3][0];
#pragma unroll
    for (int kb = 0; kb < 2; kb++)
#pragma unroll
      for (int i = 0; i < 2; i++) {
        int c  = i * 512 + tid;            // chunk within this kb-half
        int r  = c >> 3;                   // 0..127
        int sc = ((c & 7) ^ (r & 7)) << 4; // pre-swizzled global source col
        GLD_LDS16(src + (size_t)r * 256 + kb * 128 + sc,
                  dst + kb * 16384 + c * 16);
      }
  };

  // A fragments straight to registers, once (16 dwordx4 per thread).
  const unsigned char* aB = gA + (size_t)(row0 + wm * 64 + l15) * 256 + q * 32;
  i32x8 af[2][4];
#pragma unroll
  for (int kb = 0; kb < 2; kb++)
#pragma unroll
    for (int mi = 0; mi < 4; mi++)
      af[kb][mi] = *(const i32x8*)(aB + mi * 16 * 256 + kb * 128);
  __builtin_amdgcn_sched_barrier(0);   // pin: A loads issue before B stages

  stageB(0);
  stageB(1);
  stageB(2);
  __builtin_amdgcn_sched_barrier(0);

#pragma unroll
  for (int t = 0; t < 8; t++) {
    if      (t == 0) TILE_WAIT(7);
    else if (t == 1) TILE_WAIT(8);
    else if (t == 2) TILE_WAIT(9);
    else if (t == 3) TILE_WAIT(10);
    else if (t == 4) TILE_WAIT(10);
    else if (t == 5) TILE_WAIT(10);
    else if (t == 6) TILE_WAIT(6);
    else             TILE_WAIT(2);

    if (t < 5) {
      stageB(t + 3);
      __builtin_amdgcn_sched_barrier(0);
    }

    const unsigned char* bufB = &Bs[t & 3][0];

    // All B fragments for this tile (both kb halves): 16 ds_read_b128.
    i32x8 bf[2][4];
#pragma unroll
    for (int kb = 0; kb < 2; kb++)
#pragma unroll
      for (int ni = 0; ni < 4; ni++) {
        int r  = wn * 64 + ni * 16 + l15;           // 0..127
        int c0 = (q * 2)     ^ (r & 7);
        int c1 = (q * 2 + 1) ^ (r & 7);
        i32x4 lo = *(const i32x4*)(bufB + kb * 16384 + r * 128 + c0 * 16);
        i32x4 hi = *(const i32x4*)(bufB + kb * 16384 + r * 128 + c1 * 16);
        bf[kb][ni] = (i32x8){lo.x, lo.y, lo.z, lo.w, hi.x, hi.y, hi.z, hi.w};
      }

    // mi-outer: 8 MFMAs for mi, then mi's epilogue slice -- the slice's
    // exp2/adds/shuffles (trans/VALU/DS pipes) overlap mi+1's MFMAs.
    float s0, s1, s2, s3;
#pragma unroll
    for (int mi = 0; mi < 4; mi++) {
      f32x4 acc[4];
#pragma unroll
      for (int ni = 0; ni < 4; ni++) acc[ni] = (f32x4){0.f, 0.f, 0.f, 0.f};
#pragma unroll
      for (int kb = 0; kb < 2; kb++)
#pragma unroll
        for (int ni = 0; ni < 4; ni++)
          acc[ni] = __builtin_amdgcn_mfma_scale_f32_16x16x128_f8f6f4(
              bf[kb][ni], af[kb][mi], acc[ni],      // SWAPPED: D[col][row]
              0, 0, 0, kUnitScale, 0, kUnitScale);
      float v = 0.f;
#pragma unroll
      for (int ni = 0; ni < 4; ni++)
#pragma unroll
        for (int rr = 0; rr < 4; rr++)
          v += __builtin_amdgcn_exp2f(acc[ni][rr] * kLog2eHalf);
      v += __shfl_xor(v, 16, 64);
      v += __shfl_xor(v, 32, 64);
      if (mi == 0) s0 = v; else if (mi == 1) s1 = v;
      else if (mi == 2) s2 = v; else s3 = v;
    }
    float o = q == 0 ? s0 : q == 1 ? s1 : q == 2 ? s2 : s3;
    int slab = cg * 16 + t * 2 + wn;                // 64-col slab, 0..127
    partial[(size_t)slab * N + row0 + wm * 64 + q * 16 + l15] = o;
    __builtin_amdgcn_sched_barrier(0);   // pin: store issues before next stage
  }
}

// out = mean(ln(sum_j partial[j][row])) - 0.5*mean(posPart). UNCHANGED
// (partial is [M/64=128][N]).
__global__ __launch_bounds__(256) void finalize_kernel(
    const float* __restrict__ partial, const float* __restrict__ posPart,
    float* __restrict__ out, int N, int slabsPerGroup, float invN) {
  __shared__ float red[4][64];
  int t  = threadIdx.x;
  int rl = t & 63, g = t >> 6;
  int row = blockIdx.x * 64 + rl;
  const float* p = partial + (size_t)(g * slabsPerGroup) * N + row;
  float s = 0.f;
#pragma unroll 8
  for (int j = 0; j < slabsPerGroup; j++) s += p[(size_t)j * N];
  red[g][rl] = s;
  __syncthreads();
  if (t < 64) {
    float tot = red[0][rl] + red[1][rl] + red[2][rl] + red[3][rl];
    float v = __builtin_amdgcn_logf(tot) * 0.69314718055994531f
              - 0.5f * posPart[row];
#pragma unroll
    for (int m = 32; m >= 1; m >>= 1) v += __shfl_xor(v, m, 64);
    if (rl == 0) atomicAdd(out, v * invN);
  }
}

extern "C" void kernel_launch(void* const* d_in, const int* in_sizes, int n_in,
                              void* d_out, int out_size, void* d_ws, size_t ws_size,
                              hipStream_t stream) {
  const float* pk = (const float*)d_in[0];
  const float* pv = (const float*)d_in[1];
  const float* nv = (const float*)d_in[2];
  int N = in_sizes[0] / DIM;   // 8192
  int M = in_sizes[2] / DIM;   // 8192
  float* out = (float*)d_out;

  unsigned char* pkn = (unsigned char*)d_ws;                   // [N,256] fp8
  unsigned char* nvn = pkn + (size_t)N * DIM;                  // [M,256] fp8
  float* partial = (float*)(nvn + (size_t)M * DIM);            // [M/64][N] fp32
  float* posPart = partial + (size_t)(M / 64) * N;             // [N] fp32

  normalize_kernel<<<(N + M) / 4, 256, 0, stream>>>(
      (const float4*)pk, (const float4*)pv, (const float4*)nv,
      (unsigned int*)pkn, (unsigned int*)nvn, posPart, out, N);

  // grid: x = col-group (M/1024 = 8, one per XCD slot), y = row panel (32).
  gemm_lse_kernel<<<dim3(M / 1024, N / 256), 512, 0, stream>>>(
      pkn, nvn, partial, N);

  finalize_kernel<<<N / 64, 256, 0, stream>>>(
      partial, posPart, out, N, (M / 64) / 4, 1.0f / (float)N);
}